// Round 12
// baseline (167.606 us; speedup 1.0000x reference)
//
#include <hip/hip_runtime.h>
#include <stdint.h>

#define BB 8
#define SS 4096
#define DD 768
#define NN 64
#define D4 (DD / 4)        // 192 float4 columns
#define CHT 128            // tokens per chunk
#define MAXCH 96           // max chunks per batch: 64 + 4032/128 = 95 <= 96
#define NREC (BB * MAXCH)  // 768 chunk records
#define TROWS 6            // token rows per LDS tile
#define BLOCK 192          // 3 waves; thread <-> float4-column bijection
// ws layout: float sum[NREC][DD] (2,359,296 B) then u8 cnt[NREC][DD] (589,824 B)
// total 2,949,120 B <= ws_size. No zero-init: every record read by finalize
// is written by exactly one owner block.

// async global->LDS, 16 B/lane. LDS dest is wave-uniform base + lane*16
// (m104/m108): we pass l = base + lane so the layout matches.
__device__ __forceinline__ void dma16(const float* g, float4* l) {
    __builtin_amdgcn_global_load_lds(
        (const __attribute__((address_space(1))) unsigned int*)g,
        (__attribute__((address_space(3))) unsigned int*)l,
        16, 0, 0);
}

// ---------------- Phase B: LDS-DMA pipelined chunk partials ----------------
// grid: (MAXCH, BB), block 192 (3 waves). Block (cidx,b) owns one chunk
// (<=128 tokens inside one segment). Tokens stream through a double-buffered
// 6-row LDS tile via global_load_lds (wave w stages rows 2w,2w+1; 3 x 1 KiB
// insts per row). Fine-grained s_waitcnt vmcnt(6) keeps the next tile's 6
// loads in flight across the barrier (never vmcnt(0) mid-stream). Thread tid
// owns float4-column tid for the whole chunk -> no cross-wave reduce; plain
// stores to a unique record.
__global__ __launch_bounds__(BLOCK) void chunk_kernel(
    const float* __restrict__ wv,
    const int* __restrict__ lens,
    float* __restrict__ ws_sum,
    unsigned char* __restrict__ ws_cnt)
{
    __shared__ float4 tiles[2][TROWS][D4];   // 36 KB

    const int cidx = blockIdx.x;     // chunk slot within batch
    const int b    = blockIdx.y;
    const int tid  = threadIdx.x;
    const int lane = tid & 63;
    const int w    = tid >> 6;       // 0..2

    // per-wave redundant scans over the 64 segment lengths
    const int l    = lens[b * NN + lane];
    const int nchl = (l + CHT - 1) >> 7;      // chunks in this segment
    int inclen = l, inch = nchl;
    #pragma unroll
    for (int off = 1; off < 64; off <<= 1) {
        int a = __shfl_up(inclen, off); if (lane >= off) inclen += a;
        int c = __shfl_up(inch,   off); if (lane >= off) inch   += c;
    }
    const int total_ch = __shfl(inch, 63);
    if (cidx >= total_ch) return;             // uniform: whole block exits

    // owning segment: first n with inclusive chunk-scan > cidx
    unsigned long long m = __ballot(inch > cidx);
    const int n         = __ffsll(m) - 1;
    const int seg_len   = __shfl(l, n);
    const int seg_start = __shfl(inclen, n) - seg_len;
    const int ch_base   = __shfl(inch, n) - __shfl(nchl, n);
    const int t0 = seg_start + (cidx - ch_base) * CHT;
    const int t1 = min(seg_start + seg_len, t0 + CHT);

    const float* wvb = wv + (size_t)b * SS * DD;

    // stage tile rows [tb, tb+6) into buffer bf; rows beyond t1 clamp to
    // t1-1 (valid, ignored at consume) so the in-flight count is always 6.
    auto stage = [&](int bf, int tb) {
        #pragma unroll
        for (int rr = 0; rr < 2; ++rr) {
            const int r   = 2 * w + rr;
            const int tok = min(tb + r, t1 - 1);
            const float* g = wvb + (size_t)tok * DD + lane * 4;
            float4* ld = &tiles[bf][r][lane];
            dma16(g,       ld);
            dma16(g + 256, ld + 64);
            dma16(g + 512, ld + 128);
        }
    };

    float4 s = make_float4(0.f, 0.f, 0.f, 0.f);
    float4 c = make_float4(0.f, 0.f, 0.f, 0.f);
    const int ntiles = (t1 - t0 + TROWS - 1) / TROWS;

    stage(0, t0);
    for (int it = 0; it < ntiles; ++it) {
        const int bf = it & 1;
        if (it + 1 < ntiles) {
            stage(bf ^ 1, t0 + (it + 1) * TROWS);
            __asm__ __volatile__("s_waitcnt vmcnt(6)" ::: "memory");
        } else {
            __asm__ __volatile__("s_waitcnt vmcnt(0)" ::: "memory");
        }
        __asm__ __volatile__("s_barrier" ::: "memory");

        const int tb   = t0 + it * TROWS;
        const int rmax = min(TROWS, t1 - tb);   // uniform
        for (int r = 0; r < rmax; ++r) {
            float4 v = tiles[bf][r][tid];
            s.x += v.x; s.y += v.y; s.z += v.z; s.w += v.w;
            c.x += (v.x != 0.f) ? 1.f : 0.f;
            c.y += (v.y != 0.f) ? 1.f : 0.f;
            c.z += (v.z != 0.f) ? 1.f : 0.f;
            c.w += (v.w != 0.f) ? 1.f : 0.f;
        }
        __asm__ __volatile__("s_barrier" ::: "memory");
    }

    const size_t rec = (size_t)(b * MAXCH + cidx);
    ((float4*)ws_sum)[rec * D4 + tid] = s;
    uchar4 u;                      // chunk counts <= 128, exact in u8
    u.x = (unsigned char)c.x; u.y = (unsigned char)c.y;
    u.z = (unsigned char)c.z; u.w = (unsigned char)c.w;
    ((uchar4*)ws_cnt)[rec * D4 + tid] = u;
}

// ---------------- Phase C: finalize (mean, fallback, rep, masks) -----------
// grid: BB*NN = 512 blocks, 256 threads (192 active cols). Gathers the
// segment's K chunk records, then proven epilogue. (Unchanged from R8-R11.)
__global__ __launch_bounds__(256) void finalize_kernel(
    const float* __restrict__ wv,
    const int* __restrict__ rep_ids,
    const float* __restrict__ rep_mask,
    const int* __restrict__ lens,
    const float* __restrict__ len_mask,
    const float* __restrict__ ws_sum,
    const unsigned char* __restrict__ ws_cnt,
    float* __restrict__ out)
{
    __shared__ float s_part[4];
    __shared__ int s_info[2];
    const int sgid = blockIdx.x;          // b*NN + n
    const int b = sgid >> 6, n = sgid & 63;
    const int tid = threadIdx.x;
    const int lane = tid & 63;

    if (tid < 64) {                       // wave 0: chunk-base scan
        const int l    = lens[b * NN + tid];
        const int nchl = (l + CHT - 1) >> 7;
        int inch = nchl;
        #pragma unroll
        for (int off = 1; off < 64; off <<= 1) {
            int a = __shfl_up(inch, off); if (lane >= off) inch += a;
        }
        if (tid == n) { s_info[0] = inch - nchl; s_info[1] = nchl; }
    }
    __syncthreads();
    const int ch_base = s_info[0];
    const int K       = s_info[1];
    const bool active = tid < D4;

    float4 S = make_float4(0,0,0,0), C = S;
    if (active) {
        for (int k = 0; k < K; ++k) {
            const size_t rec = (size_t)(b * MAXCH + ch_base + k);
            float4 sv = ((const float4*)ws_sum)[rec * D4 + tid];
            uchar4 cv = ((const uchar4*)ws_cnt)[rec * D4 + tid];
            S.x += sv.x; S.y += sv.y; S.z += sv.z; S.w += sv.w;
            C.x += (float)cv.x; C.y += (float)cv.y;
            C.z += (float)cv.z; C.w += (float)cv.w;
        }
    }

    float tot = C.x + C.y + C.z + C.w;    // 0 for inactive lanes
    #pragma unroll
    for (int off = 32; off; off >>= 1) tot += __shfl_xor(tot, off);
    if ((tid & 63) == 0) s_part[tid >> 6] = tot;
    __syncthreads();
    const float total = s_part[0] + s_part[1] + s_part[2] + s_part[3];

    if (active) {
        float4 mean;
        mean.x = S.x / fmaxf(C.x, 1.f);
        mean.y = S.y / fmaxf(C.y, 1.f);
        mean.z = S.z / fmaxf(C.z, 1.f);
        mean.w = S.w / fmaxf(C.w, 1.f);
        if (total == 0.f) mean = ((const float4*)wv)[tid];   // wv[0,0,:]

        const float lm = len_mask[sgid];
        mean.x *= lm; mean.y *= lm; mean.z *= lm; mean.w *= lm;

        float4* out4 = (float4*)out;
        out4[(size_t)(b * 2 * NN + NN + n) * D4 + tid] = mean;

        const int   rid = rep_ids[sgid];
        const float rm  = rep_mask[sgid];
        float4 rv = ((const float4*)wv)[(size_t)(b * SS + rid) * D4 + tid];
        rv.x *= rm; rv.y *= rm; rv.z *= rm; rv.w *= rm;
        out4[(size_t)(b * 2 * NN + n) * D4 + tid] = rv;

        if (tid == 0) {
            float* masks = out + (size_t)BB * 2 * NN * DD;
            masks[b * 2 * NN + n]      = rm;
            masks[b * 2 * NN + NN + n] = lm;
        }
    }
}

extern "C" void kernel_launch(void* const* d_in, const int* in_sizes, int n_in,
                              void* d_out, int out_size, void* d_ws, size_t ws_size,
                              hipStream_t stream) {
    const float* wv       = (const float*)d_in[0];
    const int*   rep_ids  = (const int*)d_in[1];
    const float* rep_mask = (const float*)d_in[2];
    const int*   lens     = (const int*)d_in[3];
    const float* len_mask = (const float*)d_in[4];
    float*       out      = (float*)d_out;
    float*         ws_sum = (float*)d_ws;
    unsigned char* ws_cnt = (unsigned char*)d_ws + (size_t)NREC * DD * 4;

    dim3 gridB(MAXCH, BB);
    chunk_kernel<<<gridB, BLOCK, 0, stream>>>(wv, lens, ws_sum, ws_cnt);
    finalize_kernel<<<BB * NN, 256, 0, stream>>>(wv, rep_ids, rep_mask, lens,
                                                 len_mask, ws_sum, ws_cnt, out);
}

// Round 13
// 156.860 us; speedup vs baseline: 1.0685x; 1.0685x over previous
//
#include <hip/hip_runtime.h>

#define BB 8
#define SS 4096
#define DD 768
#define NN 64
#define D4 (DD / 4)        // 192 float4 columns
#define CHT 128            // tokens per chunk
#define MAXCH 96           // max chunks per batch: 64 + 4032/128 = 95 <= 96
#define NREC (BB * MAXCH)  // 768 chunk records
// ws layout: float sum[NREC][DD] (2,359,296 B) then u8 cnt[NREC][DD] (589,824 B)
// total 2,949,120 B <= ws_size. No zero-init: every record read by finalize
// is written by exactly one owner block.

// native vector type accepted by __builtin_nontemporal_load (float4 is a
// HIP_vector_type class, which the builtin rejects; this is layout-identical)
typedef float nfloat4 __attribute__((ext_vector_type(4)));

// ---------------- Phase B: balanced chunk partials, NO atomics --------------
// grid: (MAXCH, BB, 3), block 256 (4 waves). Block (cidx,b,g) locates its
// chunk (<=128 tokens, wholly inside one segment) via wave scans, streams
// tokens stride-4-waves reading float4 col g*64+lane with NON-TEMPORAL loads,
// LDS-reduces, writes its 64-col record slice with plain stores.
// Measured (R10): best variant — demand-read wall ~2.3 TB/s is the binding
// constraint; contiguous full-row (R11) and LDS-DMA (R12) variants are
// neutral/worse. Do not "optimize" the access pattern without new evidence.
__global__ __launch_bounds__(256) void chunk_kernel(
    const float* __restrict__ wv,
    const int* __restrict__ lens,
    float* __restrict__ ws_sum,
    unsigned char* __restrict__ ws_cnt)
{
    const int cidx = blockIdx.x;     // chunk slot within batch
    const int b    = blockIdx.y;
    const int g    = blockIdx.z;     // colgroup 0..2
    const int tid  = threadIdx.x;
    const int lane = tid & 63;
    const int w    = tid >> 6;       // 0..3

    // per-wave redundant scans over the 64 segment lengths
    const int l    = lens[b * NN + lane];
    const int nchl = (l + CHT - 1) >> 7;      // chunks in this segment
    int inclen = l, inch = nchl;
    #pragma unroll
    for (int off = 1; off < 64; off <<= 1) {
        int a = __shfl_up(inclen, off); if (lane >= off) inclen += a;
        int c = __shfl_up(inch,   off); if (lane >= off) inch   += c;
    }
    const int total_ch = __shfl(inch, 63);
    if (cidx >= total_ch) return;             // uniform: whole block exits

    // owning segment: first n with inclusive chunk-scan > cidx
    unsigned long long m = __ballot(inch > cidx);
    const int n         = __ffsll(m) - 1;
    const int seg_len   = __shfl(l, n);
    const int seg_start = __shfl(inclen, n) - seg_len;
    const int ch_base   = __shfl(inch, n) - __shfl(nchl, n);
    const int t0 = seg_start + (cidx - ch_base) * CHT;
    const int t1 = min(seg_start + seg_len, t0 + CHT);

    const int col4 = g * 64 + lane;
    const nfloat4* base = (const nfloat4*)wv + (size_t)b * SS * D4 + col4;

    float4 s = make_float4(0.f, 0.f, 0.f, 0.f);
    float4 c = make_float4(0.f, 0.f, 0.f, 0.f);
    #pragma unroll 8
    for (int t = t0 + w; t < t1; t += 4) {
        nfloat4 v = __builtin_nontemporal_load(base + (size_t)t * D4);
        s.x += v.x; s.y += v.y; s.z += v.z; s.w += v.w;
        c.x += (v.x != 0.f) ? 1.f : 0.f;
        c.y += (v.y != 0.f) ? 1.f : 0.f;
        c.z += (v.z != 0.f) ? 1.f : 0.f;
        c.w += (v.w != 0.f) ? 1.f : 0.f;
    }

    __shared__ float4 s_s[4][64];
    __shared__ float4 s_c[4][64];
    s_s[w][lane] = s;
    s_c[w][lane] = c;
    __syncthreads();

    if (tid < 64) {
        float4 S = make_float4(0.f, 0.f, 0.f, 0.f);
        float4 C = make_float4(0.f, 0.f, 0.f, 0.f);
        #pragma unroll
        for (int j = 0; j < 4; ++j) {
            float4 a = s_s[j][tid], d = s_c[j][tid];
            S.x += a.x; S.y += a.y; S.z += a.z; S.w += a.w;
            C.x += d.x; C.y += d.y; C.z += d.z; C.w += d.w;
        }
        const size_t rec = (size_t)(b * MAXCH + cidx);
        ((float4*)ws_sum)[rec * D4 + g * 64 + tid] = S;
        uchar4 u;                      // chunk counts <= 128, exact in u8
        u.x = (unsigned char)C.x; u.y = (unsigned char)C.y;
        u.z = (unsigned char)C.z; u.w = (unsigned char)C.w;
        ((uchar4*)ws_cnt)[rec * D4 + g * 64 + tid] = u;
    }
}

// ---------------- Phase C: finalize (mean, fallback, rep, masks) -----------
// grid: BB*NN = 512 blocks, 256 threads (192 active cols). Gathers the
// segment's K chunk records, then proven epilogue.
__global__ __launch_bounds__(256) void finalize_kernel(
    const float* __restrict__ wv,
    const int* __restrict__ rep_ids,
    const float* __restrict__ rep_mask,
    const int* __restrict__ lens,
    const float* __restrict__ len_mask,
    const float* __restrict__ ws_sum,
    const unsigned char* __restrict__ ws_cnt,
    float* __restrict__ out)
{
    __shared__ float s_part[4];
    __shared__ int s_info[2];
    const int sgid = blockIdx.x;          // b*NN + n
    const int b = sgid >> 6, n = sgid & 63;
    const int tid = threadIdx.x;
    const int lane = tid & 63;

    if (tid < 64) {                       // wave 0: chunk-base scan
        const int l    = lens[b * NN + tid];
        const int nchl = (l + CHT - 1) >> 7;
        int inch = nchl;
        #pragma unroll
        for (int off = 1; off < 64; off <<= 1) {
            int a = __shfl_up(inch, off); if (lane >= off) inch += a;
        }
        if (tid == n) { s_info[0] = inch - nchl; s_info[1] = nchl; }
    }
    __syncthreads();
    const int ch_base = s_info[0];
    const int K       = s_info[1];
    const bool active = tid < D4;

    float4 S = make_float4(0,0,0,0), C = S;
    if (active) {
        for (int k = 0; k < K; ++k) {
            const size_t rec = (size_t)(b * MAXCH + ch_base + k);
            float4 sv = ((const float4*)ws_sum)[rec * D4 + tid];
            uchar4 cv = ((const uchar4*)ws_cnt)[rec * D4 + tid];
            S.x += sv.x; S.y += sv.y; S.z += sv.z; S.w += sv.w;
            C.x += (float)cv.x; C.y += (float)cv.y;
            C.z += (float)cv.z; C.w += (float)cv.w;
        }
    }

    float tot = C.x + C.y + C.z + C.w;    // 0 for inactive lanes
    #pragma unroll
    for (int off = 32; off; off >>= 1) tot += __shfl_xor(tot, off);
    if ((tid & 63) == 0) s_part[tid >> 6] = tot;
    __syncthreads();
    const float total = s_part[0] + s_part[1] + s_part[2] + s_part[3];

    if (active) {
        float4 mean;
        mean.x = S.x / fmaxf(C.x, 1.f);
        mean.y = S.y / fmaxf(C.y, 1.f);
        mean.z = S.z / fmaxf(C.z, 1.f);
        mean.w = S.w / fmaxf(C.w, 1.f);
        if (total == 0.f) mean = ((const float4*)wv)[tid];   // wv[0,0,:]

        const float lm = len_mask[sgid];
        mean.x *= lm; mean.y *= lm; mean.z *= lm; mean.w *= lm;

        float4* out4 = (float4*)out;
        out4[(size_t)(b * 2 * NN + NN + n) * D4 + tid] = mean;

        const int   rid = rep_ids[sgid];
        const float rm  = rep_mask[sgid];
        float4 rv = ((const float4*)wv)[(size_t)(b * SS + rid) * D4 + tid];
        rv.x *= rm; rv.y *= rm; rv.z *= rm; rv.w *= rm;
        out4[(size_t)(b * 2 * NN + n) * D4 + tid] = rv;

        if (tid == 0) {
            float* masks = out + (size_t)BB * 2 * NN * DD;
            masks[b * 2 * NN + n]      = rm;
            masks[b * 2 * NN + NN + n] = lm;
        }
    }
}

extern "C" void kernel_launch(void* const* d_in, const int* in_sizes, int n_in,
                              void* d_out, int out_size, void* d_ws, size_t ws_size,
                              hipStream_t stream) {
    const float* wv       = (const float*)d_in[0];
    const int*   rep_ids  = (const int*)d_in[1];
    const float* rep_mask = (const float*)d_in[2];
    const int*   lens     = (const int*)d_in[3];
    const float* len_mask = (const float*)d_in[4];
    float*       out      = (float*)d_out;
    float*         ws_sum = (float*)d_ws;
    unsigned char* ws_cnt = (unsigned char*)d_ws + (size_t)NREC * DD * 4;

    dim3 gridB(MAXCH, BB, 3);
    chunk_kernel<<<gridB, 256, 0, stream>>>(wv, lens, ws_sum, ws_cnt);
    finalize_kernel<<<BB * NN, 256, 0, stream>>>(wv, rep_ids, rep_mask, lens,
                                                 len_mask, ws_sum, ws_cnt, out);
}